// Round 6
// baseline (147.778 us; speedup 1.0000x reference)
//
#include <hip/hip_runtime.h>

// BatchRelationalModule: B=32, C=128, H=W=12 -> L=144, D=129, HID=64
// out[b,k] = MLP( sum_{i,j} leaky( leaky(gi[b,j,:]+gj[b,i,:]+b1) @ W2 + b2 )[k] )
//
// Round 6: fold the final MLP into k_pairs via a last-block-done tail
// (counter zeroed by k_proj; __threadfence release/acquire around it).
// Two dispatches total. Reduction + MLP arithmetic bitwise-identical to the
// old k_mlp (yb ascending, same fma order) -> absmax should stay 128.

#define B_   32
#define C_   128
#define L_   144
#define HID_ 64
#define D_   129
#define STR  68   // floats per LDS row: 16B-aligned, +4 skew -> <=2-way banks (free)
#define YB_  18   // k_pairs grid.y (i-tiles of 8)
#define PL_  12   // k_proj l's per block
#define NBLK (B_ * YB_)

typedef __bf16 bf16x8 __attribute__((ext_vector_type(8)));
typedef float  floatx4 __attribute__((ext_vector_type(4)));

__device__ __forceinline__ float leaky(float x) { return fmaxf(x, 0.01f * x); }
__device__ __forceinline__ floatx4 leaky4(floatx4 x) {
    return __builtin_elementwise_max(x, x * 0.01f);
}

// ---------------- kernel 1: gi / gjb projection (W-half in LDS) -------------
// grid = (B_*2, L_/PL_): x = b*2 + which (0: gi, 1: gjb=gj+b1), y = l-tile.
// Block (0,0) also zeroes the completion counter for k_pairs.
__global__ __launch_bounds__(256) void k_proj(const float* __restrict__ x_img,
                                              const float* __restrict__ W1,
                                              const float* __restrict__ b1,
                                              float* __restrict__ gi,
                                              float* __restrict__ gjb,
                                              int* __restrict__ counter)
{
    __shared__ float sW[D_ * HID_];            // 33024 B -> 4 blocks/CU
    const int t     = threadIdx.x;
    const int b     = blockIdx.x >> 1;
    const int which = blockIdx.x & 1;
    const int l0    = blockIdx.y * PL_;

    if (blockIdx.x == 0 && blockIdx.y == 0 && t == 0)
        *counter = 0;                          // visible to k_pairs via stream order

    // stage this block's W1 half (129 x 64 fp32)
    {
        const floatx4* w4 = (const floatx4*)(W1 + which * (D_ * HID_));
        floatx4* s4 = (floatx4*)sW;
        for (int idx = t; idx < D_ * HID_ / 4; idx += 256)   // 2064 float4
            s4[idx] = w4[idx];
    }
    __syncthreads();

    const int h    = t & 63;
    const int wave = t >> 6;
    float* outp  = which ? gjb : gi;
    const float bias = which ? b1[h] : 0.f;

#pragma unroll
    for (int il = 0; il < PL_ / 4; ++il) {     // 3 l's per wave
        const int l = l0 + wave * (PL_ / 4) + il;
        const float* xp = x_img + (size_t)(b * C_) * L_ + l;

        float a0 = fmaf((float)l, sW[C_ * HID_ + h], bias);
        float a1 = 0.f;
#pragma unroll 4
        for (int c = 0; c < C_; c += 2) {
            a0 = fmaf(xp[c * L_],       sW[c * HID_ + h],       a0);
            a1 = fmaf(xp[(c + 1) * L_], sW[(c + 1) * HID_ + h], a1);
        }
        outp[(b * L_ + l) * HID_ + h] = a0 + a1;
    }
}

// ---------------- kernel 2: pairwise MFMA core + fused final MLP ------------
// grid = (B_, YB_), 256 threads = 4 waves. Each wave: 2 i's x 9 j-tiles of 16.
__global__ __launch_bounds__(256, 4) void k_pairs(const float* __restrict__ gi,
                                                  const float* __restrict__ gjb,
                                                  const float* __restrict__ W2,
                                                  const float* __restrict__ b2,
                                                  const float* __restrict__ Wp,
                                                  const float* __restrict__ bp,
                                                  const float* __restrict__ Wo,
                                                  const float* __restrict__ bo,
                                                  float* __restrict__ partial,
                                                  int* __restrict__ counter,
                                                  float* __restrict__ out)
{
    __shared__ float s_gi[L_ * STR];           // 39168 B -> 4 blocks/CU
    __shared__ int   isLast;

    const int t    = threadIdx.x;
    const int wave = t >> 6;
    const int lane = t & 63;
    const int m    = lane & 15;        // A row / C col index
    const int quad = lane >> 4;        // k-subchunk selector
    const int b    = blockIdx.x;

    // ---- stage gi b-slice into LDS; float4 both sides ----------------------
    {
        const floatx4* g4i = (const floatx4*)(gi + (size_t)b * (L_ * HID_));
        for (int idx = t; idx < L_ * HID_ / 4; idx += 256) {  // 2304 float4
            int l  = idx >> 4;             // 16 float4 per row
            int c4 = idx & 15;
            *(floatx4*)&s_gi[l * STR + c4 * 4] = g4i[idx];
        }
    }

    // ---- W2 -> B-fragments in registers (once per wave) --------------------
    bf16x8 Bf[2][4];
#pragma unroll
    for (int kc = 0; kc < 2; ++kc)
#pragma unroll
        for (int nt = 0; nt < 4; ++nt)
#pragma unroll
            for (int j = 0; j < 8; ++j)
                Bf[kc][nt][j] = (__bf16)W2[(kc * 32 + quad * 8 + j) * HID_ + nt * 16 + m];

    float b2v[4];
#pragma unroll
    for (int nt = 0; nt < 4; ++nt) b2v[nt] = b2[nt * 16 + m];

    floatx4 sacc[4];
#pragma unroll
    for (int nt = 0; nt < 4; ++nt) sacc[nt] = floatx4{0.f, 0.f, 0.f, 0.f};

    const int h0 = quad * 8;

    __syncthreads();

    // ---- main loop: 2 i's per wave, 9 j-tiles each -------------------------
#pragma unroll
    for (int ii = 0; ii < 2; ++ii) {
        const int i = (blockIdx.y * 4 + wave) * 2 + ii;   // 0..143

        const float* gjr = gjb + ((size_t)b * L_ + i) * HID_;
        floatx4 gjA0 = *(const floatx4*)(gjr + h0);
        floatx4 gjA1 = *(const floatx4*)(gjr + h0 + 4);
        floatx4 gjB0 = *(const floatx4*)(gjr + 32 + h0);
        floatx4 gjB1 = *(const floatx4*)(gjr + 32 + h0 + 4);

        for (int jt = 0; jt < 9; ++jt) {
            const float* gr = &s_gi[(jt * 16 + m) * STR];

            floatx4 va0 = *(const floatx4*)(gr + h0)          + gjA0;
            floatx4 va1 = *(const floatx4*)(gr + h0 + 4)      + gjA1;
            floatx4 vb0 = *(const floatx4*)(gr + 32 + h0)     + gjB0;
            floatx4 vb1 = *(const floatx4*)(gr + 32 + h0 + 4) + gjB1;
            va0 = leaky4(va0); va1 = leaky4(va1);
            vb0 = leaky4(vb0); vb1 = leaky4(vb1);

            bf16x8 A0, A1;
#pragma unroll
            for (int j = 0; j < 4; ++j) {
                A0[j]     = (__bf16)va0[j];
                A0[4 + j] = (__bf16)va1[j];
                A1[j]     = (__bf16)vb0[j];
                A1[4 + j] = (__bf16)vb1[j];
            }

            floatx4 Cf[4];
#pragma unroll
            for (int nt = 0; nt < 4; ++nt) {
                Cf[nt] = floatx4{0.f, 0.f, 0.f, 0.f};
                Cf[nt] = __builtin_amdgcn_mfma_f32_16x16x32_bf16(A0, Bf[0][nt], Cf[nt], 0, 0, 0);
                Cf[nt] = __builtin_amdgcn_mfma_f32_16x16x32_bf16(A1, Bf[1][nt], Cf[nt], 0, 0, 0);
            }

#pragma unroll
            for (int nt = 0; nt < 4; ++nt)
                sacc[nt] += leaky4(Cf[nt] + b2v[nt]);
        }
    }

    // ---- reduce quad-groups in-wave, then block-reduce via LDS -------------
    float red[4];
#pragma unroll
    for (int nt = 0; nt < 4; ++nt) {
        float s = sacc[nt][0] + sacc[nt][1] + sacc[nt][2] + sacc[nt][3];
        s += __shfl_xor(s, 16, 64);
        s += __shfl_xor(s, 32, 64);
        red[nt] = s;                      // valid in quad==0 lanes (m = col)
    }
    __syncthreads();                      // LDS reads of main loop done
    if (quad == 0) {
#pragma unroll
        for (int nt = 0; nt < 4; ++nt)
            s_gi[wave * STR + nt * 16 + m] = red[nt];
    }
    __syncthreads();
    if (t < HID_) {
        float s = s_gi[0 * STR + t] + s_gi[1 * STR + t]
                + s_gi[2 * STR + t] + s_gi[3 * STR + t];
        partial[(b * YB_ + blockIdx.y) * HID_ + t] = s;
    }

    // ---- last-block-done: release, count, acquire --------------------------
    __threadfence();                      // device-scope release of partial
    __syncthreads();                      // all lanes' fences done before atomic
    if (t == 0) {
        int old = atomicAdd(counter, 1);
        isLast = (old == NBLK - 1);
    }
    __syncthreads();
    if (!isLast) return;
    __threadfence();                      // device-scope acquire

    // ---- fused final MLP (single block, all 32 batches) --------------------
    float* s0 = s_gi;                     // 2048 floats
    float* s1 = s_gi + B_ * HID_;         // 2048 floats (9792 total available)

    for (int s = t; s < B_ * HID_; s += 256) {
        int bb = s >> 6, k = s & 63;
        float a = 0.f;
#pragma unroll
        for (int yb = 0; yb < YB_; ++yb)  // ascending: same order as old k_mlp
            a += partial[(bb * YB_ + yb) * HID_ + k];
        s0[s] = a;
    }
    __syncthreads();
    for (int s = t; s < B_ * HID_; s += 256) {
        int bb = s >> 6, k = s & 63;
        float v = bp[k];
#pragma unroll 8
        for (int h = 0; h < HID_; ++h)
            v = fmaf(s0[bb * HID_ + h], Wp[h * HID_ + k], v);
        s1[s] = leaky(v);
    }
    __syncthreads();
    for (int s = t; s < B_ * HID_; s += 256) {
        int bb = s >> 6, k = s & 63;
        float w = bo[k];
#pragma unroll 8
        for (int h = 0; h < HID_; ++h)
            w = fmaf(s1[bb * HID_ + h], Wo[h * HID_ + k], w);
        out[s] = leaky(w);
    }
}

// ---------------- launch ----------------------------------------------------
extern "C" void kernel_launch(void* const* d_in, const int* in_sizes, int n_in,
                              void* d_out, int out_size, void* d_ws, size_t ws_size,
                              hipStream_t stream)
{
    const float* x_img = (const float*)d_in[0];
    const float* W1    = (const float*)d_in[1];
    const float* b1    = (const float*)d_in[2];
    const float* W2    = (const float*)d_in[3];
    const float* b2    = (const float*)d_in[4];
    const float* Wp    = (const float*)d_in[5];
    const float* bp    = (const float*)d_in[6];
    const float* Wo    = (const float*)d_in[7];
    const float* bo    = (const float*)d_in[8];
    float* out = (float*)d_out;

    float* gi      = (float*)d_ws;                 // B*L*HID floats
    float* gjb     = gi + B_ * L_ * HID_;          // gj + b1, B*L*HID floats
    float* partial = gjb + B_ * L_ * HID_;         // NBLK*HID floats
    int*   counter = (int*)(partial + NBLK * HID_);

    k_proj <<<dim3(B_ * 2, L_ / PL_), 256, 0, stream>>>(x_img, W1, b1, gi, gjb, counter);
    k_pairs<<<dim3(B_, YB_),          256, 0, stream>>>(gi, gjb, W2, b2, Wp, bp, Wo, bo,
                                                        partial, counter, out);
}

// Round 7
// 106.491 us; speedup vs baseline: 1.3877x; 1.3877x over previous
//
#include <hip/hip_runtime.h>

// BatchRelationalModule: B=32, C=128, H=W=12 -> L=144, D=129, HID=64
// out[b,k] = MLP( sum_{i,j} leaky( leaky(gi[b,j,:]+gj[b,i,:]+b1) @ W2 + b2 )[k] )
//
// Round 7: exact revert to round-5 (106.1 us). Round 6's in-kernel MLP tail
// collapsed k_pairs codegen (VGPR 60 -> scratch spills in the hot loop,
// 68 us, MfmaUtil 2.8%). Keep cold tail in its own kernel (k_mlp).
//
//  - k_proj: W1-half staged in LDS (33 KB), grid (64,12); b1 folded into gjb.
//  - k_pairs: bf16 MFMA over all (i,j) pairs; only s_gi in LDS (39 KB ->
//    4 blocks/CU); gjb rows broadcast-loaded from global (L2-resident).
//  - k_mlp: 18-way partial reduce + 64->64->64 MLP.

#define B_   32
#define C_   128
#define L_   144
#define HID_ 64
#define D_   129
#define STR  68   // floats per LDS row: 16B-aligned, +4 skew -> <=2-way banks (free)
#define YB_  18   // k_pairs grid.y (i-tiles of 8)
#define PL_  12   // k_proj l's per block

typedef __bf16 bf16x8 __attribute__((ext_vector_type(8)));
typedef float  floatx4 __attribute__((ext_vector_type(4)));

__device__ __forceinline__ float leaky(float x) { return fmaxf(x, 0.01f * x); }
__device__ __forceinline__ floatx4 leaky4(floatx4 x) {
    return __builtin_elementwise_max(x, x * 0.01f);
}

// ---------------- kernel 1: gi / gjb projection (W-half in LDS) -------------
// grid = (B_*2, L_/PL_): x = b*2 + which (0: gi, 1: gjb=gj+b1), y = l-tile.
__global__ __launch_bounds__(256) void k_proj(const float* __restrict__ x_img,
                                              const float* __restrict__ W1,
                                              const float* __restrict__ b1,
                                              float* __restrict__ gi,
                                              float* __restrict__ gjb)
{
    __shared__ float sW[D_ * HID_];            // 33024 B -> 4 blocks/CU
    const int t     = threadIdx.x;
    const int b     = blockIdx.x >> 1;
    const int which = blockIdx.x & 1;
    const int l0    = blockIdx.y * PL_;

    // stage this block's W1 half (129 x 64 fp32)
    {
        const floatx4* w4 = (const floatx4*)(W1 + which * (D_ * HID_));
        floatx4* s4 = (floatx4*)sW;
        for (int idx = t; idx < D_ * HID_ / 4; idx += 256)   // 2064 float4
            s4[idx] = w4[idx];
    }
    __syncthreads();

    const int h    = t & 63;
    const int wave = t >> 6;
    float* outp  = which ? gjb : gi;
    const float bias = which ? b1[h] : 0.f;

#pragma unroll
    for (int il = 0; il < PL_ / 4; ++il) {     // 3 l's per wave
        const int l = l0 + wave * (PL_ / 4) + il;
        const float* xp = x_img + (size_t)(b * C_) * L_ + l;

        // two partial accumulators to break the fma dependency chain
        float a0 = fmaf((float)l, sW[C_ * HID_ + h], bias);
        float a1 = 0.f;
#pragma unroll 4
        for (int c = 0; c < C_; c += 2) {
            a0 = fmaf(xp[c * L_],       sW[c * HID_ + h],       a0);
            a1 = fmaf(xp[(c + 1) * L_], sW[(c + 1) * HID_ + h], a1);
        }
        outp[(b * L_ + l) * HID_ + h] = a0 + a1;
    }
}

// ---------------- kernel 2: pairwise core via MFMA --------------------------
// grid = (B_, YB_), 256 threads = 4 waves. Each wave: 2 i's x 9 j-tiles of 16.
// Writes partial[(b*YB_ + yb)*64 + k] -- no atomics, no pre-zeroing needed.
__global__ __launch_bounds__(256, 4) void k_pairs(const float* __restrict__ gi,
                                                  const float* __restrict__ gjb,
                                                  const float* __restrict__ W2,
                                                  const float* __restrict__ b2,
                                                  float* __restrict__ partial)
{
    __shared__ float s_gi[L_ * STR];           // 39168 B -> 4 blocks/CU

    const int t    = threadIdx.x;
    const int wave = t >> 6;
    const int lane = t & 63;
    const int m    = lane & 15;        // A row / C col index
    const int quad = lane >> 4;        // k-subchunk selector
    const int b    = blockIdx.x;

    // ---- stage gi b-slice into LDS; float4 both sides ----------------------
    {
        const floatx4* g4i = (const floatx4*)(gi + (size_t)b * (L_ * HID_));
        for (int idx = t; idx < L_ * HID_ / 4; idx += 256) {  // 2304 float4
            int l  = idx >> 4;             // 16 float4 per row
            int c4 = idx & 15;
            *(floatx4*)&s_gi[l * STR + c4 * 4] = g4i[idx];
        }
    }

    // ---- W2 -> B-fragments in registers (once per wave) --------------------
    bf16x8 Bf[2][4];
#pragma unroll
    for (int kc = 0; kc < 2; ++kc)
#pragma unroll
        for (int nt = 0; nt < 4; ++nt)
#pragma unroll
            for (int j = 0; j < 8; ++j)
                Bf[kc][nt][j] = (__bf16)W2[(kc * 32 + quad * 8 + j) * HID_ + nt * 16 + m];

    float b2v[4];
#pragma unroll
    for (int nt = 0; nt < 4; ++nt) b2v[nt] = b2[nt * 16 + m];

    floatx4 sacc[4];
#pragma unroll
    for (int nt = 0; nt < 4; ++nt) sacc[nt] = floatx4{0.f, 0.f, 0.f, 0.f};

    const int h0 = quad * 8;

    __syncthreads();

    // ---- main loop: 2 i's per wave, 9 j-tiles each -------------------------
#pragma unroll
    for (int ii = 0; ii < 2; ++ii) {
        const int i = (blockIdx.y * 4 + wave) * 2 + ii;   // 0..143

        // this wave's gjb row, straight from global (L2-resident, broadcast)
        const float* gjr = gjb + ((size_t)b * L_ + i) * HID_;
        floatx4 gjA0 = *(const floatx4*)(gjr + h0);
        floatx4 gjA1 = *(const floatx4*)(gjr + h0 + 4);
        floatx4 gjB0 = *(const floatx4*)(gjr + 32 + h0);
        floatx4 gjB1 = *(const floatx4*)(gjr + 32 + h0 + 4);

        for (int jt = 0; jt < 9; ++jt) {
            const float* gr = &s_gi[(jt * 16 + m) * STR];

            floatx4 va0 = *(const floatx4*)(gr + h0)          + gjA0;
            floatx4 va1 = *(const floatx4*)(gr + h0 + 4)      + gjA1;
            floatx4 vb0 = *(const floatx4*)(gr + 32 + h0)     + gjB0;
            floatx4 vb1 = *(const floatx4*)(gr + 32 + h0 + 4) + gjB1;
            va0 = leaky4(va0); va1 = leaky4(va1);
            vb0 = leaky4(vb0); vb1 = leaky4(vb1);

            bf16x8 A0, A1;
#pragma unroll
            for (int j = 0; j < 4; ++j) {
                A0[j]     = (__bf16)va0[j];
                A0[4 + j] = (__bf16)va1[j];
                A1[j]     = (__bf16)vb0[j];
                A1[4 + j] = (__bf16)vb1[j];
            }

            floatx4 Cf[4];
#pragma unroll
            for (int nt = 0; nt < 4; ++nt) {
                Cf[nt] = floatx4{0.f, 0.f, 0.f, 0.f};
                Cf[nt] = __builtin_amdgcn_mfma_f32_16x16x32_bf16(A0, Bf[0][nt], Cf[nt], 0, 0, 0);
                Cf[nt] = __builtin_amdgcn_mfma_f32_16x16x32_bf16(A1, Bf[1][nt], Cf[nt], 0, 0, 0);
            }

#pragma unroll
            for (int nt = 0; nt < 4; ++nt)
                sacc[nt] += leaky4(Cf[nt] + b2v[nt]);
        }
    }

    // ---- reduce quad-groups in-wave, then block-reduce via LDS -------------
    float red[4];
#pragma unroll
    for (int nt = 0; nt < 4; ++nt) {
        float s = sacc[nt][0] + sacc[nt][1] + sacc[nt][2] + sacc[nt][3];
        s += __shfl_xor(s, 16, 64);
        s += __shfl_xor(s, 32, 64);
        red[nt] = s;                      // valid in quad==0 lanes (m = col)
    }
    __syncthreads();                      // LDS reads of main loop done
    if (quad == 0) {
#pragma unroll
        for (int nt = 0; nt < 4; ++nt)
            s_gi[wave * STR + nt * 16 + m] = red[nt];
    }
    __syncthreads();
    if (t < HID_) {
        float s = s_gi[0 * STR + t] + s_gi[1 * STR + t]
                + s_gi[2 * STR + t] + s_gi[3 * STR + t];
        partial[(b * YB_ + blockIdx.y) * HID_ + t] = s;
    }
}

// ---------------- kernel 3: partial-reduce + final 64->64->64 MLP -----------
__global__ __launch_bounds__(64) void k_mlp(const float* __restrict__ partial,
                                            const float* __restrict__ Wp,
                                            const float* __restrict__ bp,
                                            const float* __restrict__ Wo,
                                            const float* __restrict__ bo,
                                            float* __restrict__ out)
{
    __shared__ float s0[HID_], s1[HID_];
    int b = blockIdx.x, k = threadIdx.x;

    float a = 0.f;
#pragma unroll
    for (int yb = 0; yb < YB_; ++yb)
        a += partial[(b * YB_ + yb) * HID_ + k];
    s0[k] = a;
    __syncthreads();

    float v = bp[k];
#pragma unroll 8
    for (int h = 0; h < HID_; ++h) v = fmaf(s0[h], Wp[h * HID_ + k], v);
    v = leaky(v);
    s1[k] = v;
    __syncthreads();
    float w = bo[k];
#pragma unroll 8
    for (int h = 0; h < HID_; ++h) w = fmaf(s1[h], Wo[h * HID_ + k], w);
    w = leaky(w);
    out[b * HID_ + k] = w;
}

// ---------------- launch ----------------------------------------------------
extern "C" void kernel_launch(void* const* d_in, const int* in_sizes, int n_in,
                              void* d_out, int out_size, void* d_ws, size_t ws_size,
                              hipStream_t stream)
{
    const float* x_img = (const float*)d_in[0];
    const float* W1    = (const float*)d_in[1];
    const float* b1    = (const float*)d_in[2];
    const float* W2    = (const float*)d_in[3];
    const float* b2    = (const float*)d_in[4];
    const float* Wp    = (const float*)d_in[5];
    const float* bp    = (const float*)d_in[6];
    const float* Wo    = (const float*)d_in[7];
    const float* bo    = (const float*)d_in[8];
    float* out = (float*)d_out;

    float* gi      = (float*)d_ws;                 // B*L*HID floats
    float* gjb     = gi + B_ * L_ * HID_;          // gj + b1, B*L*HID floats
    float* partial = gjb + B_ * L_ * HID_;         // B*YB_*HID floats

    k_proj <<<dim3(B_ * 2, L_ / PL_), 256, 0, stream>>>(x_img, W1, b1, gi, gjb);
    k_pairs<<<dim3(B_, YB_),          256, 0, stream>>>(gi, gjb, W2, b2, partial);
    k_mlp  <<<dim3(B_),                64, 0, stream>>>(partial, Wp, bp, Wo, bo, out);
}